// Round 12
// baseline (166.662 us; speedup 1.0000x reference)
//
#include <hip/hip_runtime.h>
#include <cstdint>
#include <cstddef>

#define NUSERS 100000
#define BB 16384

static __device__ __forceinline__ unsigned short f2bf(float x) {
    unsigned u = __float_as_uint(x);
    u += 0x7FFF + ((u >> 16) & 1);          // round-to-nearest-even
    return (unsigned short)(u >> 16);
}
static __device__ __forceinline__ float4 bf4_to_f4(ushort4 h) {
    float4 r;
    r.x = __uint_as_float((unsigned)h.x << 16);
    r.y = __uint_as_float((unsigned)h.y << 16);
    r.z = __uint_as_float((unsigned)h.z << 16);
    r.w = __uint_as_float((unsigned)h.w << 16);
    return r;
}

// ---------------- K0: per-user attention score Q[u] AND bf16 feature table.
// (byte-identical to round 7; measured marginal cost ~9.6us, near its
// streaming-traffic floor)
__global__ __launch_bounds__(256) void k0_scores(
    const float* __restrict__ features, const float* __restrict__ wg1,
    const float* __restrict__ bg1, const float* __restrict__ wg2,
    const float* __restrict__ bg2, float* __restrict__ Q,
    unsigned short* __restrict__ fbf)
{
    __shared__ float frow[16 * 68];   // 16 user rows, padded
    __shared__ float wg1t[16 * 68];   // wg1 transposed [k][d], padded
    const int tid = threadIdx.x;
    const int blk = blockIdx.x;

    const float4 v = ((const float4*)(features + (size_t)blk * 1024))[tid];
    {
        const int row = tid >> 4, q = tid & 15;
        *(float4*)&frow[row * 68 + q * 4] = v;
    }
    {
        const float4 w = ((const float4*)wg1)[tid];
        const int d = tid >> 2, k0 = (tid & 3) * 4;
        wg1t[(k0 + 0) * 68 + d] = w.x;
        wg1t[(k0 + 1) * 68 + d] = w.y;
        wg1t[(k0 + 2) * 68 + d] = w.z;
        wg1t[(k0 + 3) * 68 + d] = w.w;
    }
    {
        ushort4 o;
        o.x = f2bf(v.x); o.y = f2bf(v.y); o.z = f2bf(v.z); o.w = f2bf(v.w);
        *(ushort4*)(fbf + (size_t)blk * 1024 + tid * 4) = o;
    }
    __syncthreads();

    const int k = tid & 15, ul = tid >> 4;
    float x = bg1[k];
    #pragma unroll
    for (int d4 = 0; d4 < 16; ++d4) {
        const float4 f  = *(const float4*)&frow[ul * 68 + d4 * 4];
        const float4 wv = *(const float4*)&wg1t[k * 68 + d4 * 4];
        x += f.x * wv.x + f.y * wv.y + f.z * wv.z + f.w * wv.w;
    }
    float xx = fminf(fmaxf(x, -9.f), 9.f);
    float e2 = __expf(2.f * xx);
    float th = (e2 - 1.f) / (e2 + 1.f);
    float t = th * wg2[k];
    t += __shfl_xor(t, 1);
    t += __shfl_xor(t, 2);
    t += __shfl_xor(t, 4);
    t += __shfl_xor(t, 8);
    if (k == 0) Q[blk * 16 + ul] = t + bg2[0];
}

// ---------------- K1: round-7 code, grid DOUBLED for PMC visibility.
// Ledger after rounds 10/11: fills 89us fixed, k0 9.6us, k1 ~40us, of which
// warm-gather ~5.3us. The ~34us residual has 3 candidate explanations
// (occupancy cap / VALU-issue / cold fabric latency) with 3 different fixes.
// This round surfaces k1 ABOVE the ~44us fill floor by processing every
// element twice (blocks >= BB/4 redo elements 0..16383 idempotently; same
// values to same lines, benign race) -> k1 dispatch ~75-85us -> full PMC row.
__global__ __launch_bounds__(256) void k1_fuse(
    const int* __restrict__ nodes, const int* __restrict__ hist_u,
    const int* __restrict__ hist_r, const int* __restrict__ hist_m,
    const int* __restrict__ soc_a, const int* __restrict__ soc_m,
    const unsigned short* __restrict__ fbf, const float* __restrict__ r_embed,
    const float* __restrict__ Q, const float* __restrict__ w1,
    const float* __restrict__ b1, float* __restrict__ out)
{
    __shared__ float wvbuf[4][128];   // 2048B per-wave union:
                                      //   lifetime 1: lcomp int[96]
                                      //   lifetime 2: comb  float[128]

    const int tid  = threadIdx.x;
    const int lane = tid & 63;
    const int wv   = tid >> 6;
    const int blk  = (blockIdx.x >= BB / 4) ? (blockIdx.x - BB / 4) : blockIdx.x;
    const int e    = blk * 4 + wv;
    const int sub  = lane & 15;       // matvec role
    const int grp  = lane >> 4;       // matvec role
    const char* fb = (const char*)fbf;

    int*   lc = (int*)&wvbuf[wv][0];
    float* cb = &wvbuf[wv][0];

    // ---- zero-init merged list (tail entries: offset 0 = row 0) ----
    lc[lane] = 0;
    if (lane < 32) lc[64 + lane] = 0;

    // ---- index loads (issue ASAP) ----
    int nd = (lane < 8) ? nodes[e * 8 + lane] : 0;
    int hu = 0, hr = 0, hmv = 0;
    if (lane < 50) {
        hu  = hist_u[e * 50 + lane];
        hr  = hist_r[e * 50 + lane];
        hmv = hist_m[e * 50 + lane];
    }
    int sa = 0, sk = 0;
    if (lane < 32) {
        sa = soc_a[e * 32 + lane];
        sk = soc_m[e * 32 + lane];
    }

    // ---- ballots / counts ----
    uint64_t hb = __ballot(hmv != 0);
    const int hc = (int)__popcll(hb);
    int hrank = (int)__popcll(hb & ((1ull << lane) - 1));

    uint64_t sbm = __ballot(sk != 0);
    const int scn = (int)__popcll(sbm);
    int srank = (int)__popcll(sbm & ((1ull << lane) - 1));

    const float hw = 0.5f / (float)hc;     // hc >= 1 (mask[:,0]=True)
    const float sw = 0.5f / (float)scn;    // scn >= 1
    const int   n  = hc + scn;             // <= 82

    // ---- merged compaction: hist [0,hc), social [hc,n); byte offsets,
    //      bf16 row = 128B ----
    if (hmv) lc[hrank] = hu << 7;
    if (sk)  lc[hc + srank] = sa << 7;

    // ---- rating counts ----
    const int c0 = (int)__popcll(__ballot(hmv && hr == 0));
    const int c1 = (int)__popcll(__ballot(hmv && hr == 1));
    const int c2 = (int)__popcll(__ballot(hmv && hr == 2));
    const int c3 = (int)__popcll(__ballot(hmv && hr == 3));
    const int c4 = (int)__popcll(__ballot(hmv && hr == 4));

    // ---- read back merged list (ends lcomp lifetime) ----
    int pkA = lc[lane];
    int pkB = lc[64 + (lane & 31)];

    // ---- softmax over 8 group logits from precomputed Q (lanes 0..7) ----
    float sc = (lane < 8) ? Q[nd] : -1e30f;
    float mx = sc;
    mx = fmaxf(mx, __shfl_xor(mx, 1));
    mx = fmaxf(mx, __shfl_xor(mx, 2));
    mx = fmaxf(mx, __shfl_xor(mx, 4));
    float ex = __expf(sc - mx);
    float sm = ex;
    sm += __shfl_xor(sm, 1);
    sm += __shfl_xor(sm, 2);
    sm += __shfl_xor(sm, 4);
    float al = ex / sm;                 // valid on lanes 0..7

    // ---- member-row gathers (8 rows; 2 ushort4 per lane), alpha-weighted ----
    float4 sf4;
    {
        const float a0 = __shfl(al, grp);
        const int   u0 = __shfl(nd, grp);
        const float a1 = __shfl(al, 4 + grp);
        const int   u1 = __shfl(nd, 4 + grp);
        const float4 v0 = bf4_to_f4(*(const ushort4*)(fb + ((unsigned)u0 << 7) + sub * 8));
        const float4 v1 = bf4_to_f4(*(const ushort4*)(fb + ((unsigned)u1 << 7) + sub * 8));
        sf4.x = a0 * v0.x + a1 * v1.x;
        sf4.y = a0 * v0.y + a1 * v1.y;
        sf4.z = a0 * v0.z + a1 * v1.z;
        sf4.w = a0 * v0.w + a1 * v1.w;
    }

    // ---- merged neighbor gathers: 16 rows (4 independent loads) per iter,
    //      weight derived from entry index ----
    float4 nb4 = {0.f, 0.f, 0.f, 0.f};
    for (int base = 0; base < n; base += 16) {
        #pragma unroll
        for (int j = 0; j < 4; ++j) {
            const int cbase = base + j * 4;       // uniform, 4-aligned
            int off;
            if (cbase < 64) off = __shfl(pkA, cbase + grp);
            else            off = __shfl(pkB, cbase - 64 + grp);
            const int idx = cbase + grp;
            const float w = (idx < hc) ? hw : ((idx < n) ? sw : 0.f);
            const float4 v = bf4_to_f4(*(const ushort4*)(fb + (unsigned)off + sub * 8));
            nb4.x += w * v.x; nb4.y += w * v.y;
            nb4.z += w * v.z; nb4.w += w * v.w;
        }
    }

    // ---- cross-group reduction (sum row-slot partials; all lanes end equal) ----
#define XRED(v4)                                            \
    v4.x += __shfl_xor(v4.x, 16); v4.x += __shfl_xor(v4.x, 32); \
    v4.y += __shfl_xor(v4.y, 16); v4.y += __shfl_xor(v4.y, 32); \
    v4.z += __shfl_xor(v4.z, 16); v4.z += __shfl_xor(v4.z, 32); \
    v4.w += __shfl_xor(v4.w, 16); v4.w += __shfl_xor(v4.w, 32);
    XRED(sf4)
    XRED(nb4)
#undef XRED

    // ---- rating-count correction (scaled by 0.5/hc); re loads late ----
    {
        const float4* re4p = (const float4*)r_embed;
        const float4 re0 = re4p[0 * 16 + sub];
        const float4 re1 = re4p[1 * 16 + sub];
        const float4 re2 = re4p[2 * 16 + sub];
        const float4 re3 = re4p[3 * 16 + sub];
        const float4 re4 = re4p[4 * 16 + sub];
        float f0 = hw * (float)c0, f1 = hw * (float)c1, f2 = hw * (float)c2,
              f3 = hw * (float)c3, f4 = hw * (float)c4;
        nb4.x += f0 * re0.x + f1 * re1.x + f2 * re2.x + f3 * re3.x + f4 * re4.x;
        nb4.y += f0 * re0.y + f1 * re1.y + f2 * re2.y + f3 * re3.y + f4 * re4.y;
        nb4.z += f0 * re0.z + f1 * re1.z + f2 * re2.z + f3 * re3.z + f4 * re4.z;
        nb4.w += f0 * re0.w + f1 * re1.w + f2 * re2.w + f3 * re3.w + f4 * re4.w;
    }

    // ---- park comb row (lcomp dead; wave-local, no barrier) ----
    if (grp == 0) *(float4*)&cb[sub * 4] = sf4;
    if (grp == 1) *(float4*)&cb[64 + sub * 4] = nb4;

    // ---- fused matvec, float4 w1 loads:
    //      lane (grp,sub) accumulates cols 4sub..4sub+3 over k = 4j+grp ----
    float4 p = {0.f, 0.f, 0.f, 0.f};
    #pragma unroll 8
    for (int j = 0; j < 32; ++j) {
        const float  c   = cb[j * 4 + grp];                    // LDS broadcast
        const float4 wv4 = *(const float4*)(w1 + (j * 4 + grp) * 64 + sub * 4);
        p.x += c * wv4.x;
        p.y += c * wv4.y;
        p.z += c * wv4.z;
        p.w += c * wv4.w;
    }
    p.x += __shfl_xor(p.x, 16); p.x += __shfl_xor(p.x, 32);
    p.y += __shfl_xor(p.y, 16); p.y += __shfl_xor(p.y, 32);
    p.z += __shfl_xor(p.z, 16); p.z += __shfl_xor(p.z, 32);
    p.w += __shfl_xor(p.w, 16); p.w += __shfl_xor(p.w, 32);
    if (grp == 0) {
        const float4 bv = *(const float4*)(b1 + sub * 4);
        float4 o;
        o.x = fmaxf(p.x + bv.x, 0.f);
        o.y = fmaxf(p.y + bv.y, 0.f);
        o.z = fmaxf(p.z + bv.z, 0.f);
        o.w = fmaxf(p.w + bv.w, 0.f);
        *(float4*)(out + (size_t)e * 64 + sub * 4) = o;
    }
}

extern "C" void kernel_launch(void* const* d_in, const int* in_sizes, int n_in,
                              void* d_out, int out_size, void* d_ws, size_t ws_size,
                              hipStream_t stream)
{
    const int*   nodes    = (const int*)d_in[0];
    const int*   hu       = (const int*)d_in[1];
    const int*   hr       = (const int*)d_in[2];
    const int*   hm       = (const int*)d_in[3];
    const int*   sa       = (const int*)d_in[4];
    const int*   smk      = (const int*)d_in[5];
    const float* features = (const float*)d_in[6];
    const float* r_embed  = (const float*)d_in[7];
    const float* wg1      = (const float*)d_in[8];
    const float* bg1      = (const float*)d_in[9];
    const float* wg2      = (const float*)d_in[10];
    const float* bg2      = (const float*)d_in[11];
    const float* w1       = (const float*)d_in[12];
    const float* b1       = (const float*)d_in[13];
    float* out = (float*)d_out;

    float*          Q   = (float*)d_ws;                    // 131072 floats (512 KB)
    unsigned short* fbf = (unsigned short*)(Q + 131072);   // 100000*64 bf16 = 12.8 MB

    k0_scores<<<NUSERS / 16, 256, 0, stream>>>(features, wg1, bg1, wg2, bg2, Q, fbf);
    // DIAGNOSTIC: k1 grid doubled (idempotent second pass) for PMC visibility.
    k1_fuse<<<2 * (BB / 4), 256, 0, stream>>>(nodes, hu, hr, hm, sa, smk,
                                              fbf, r_embed, Q, w1, b1, out);
}

// Round 13
// 149.925 us; speedup vs baseline: 1.1116x; 1.1116x over previous
//
#include <hip/hip_runtime.h>
#include <cstdint>
#include <cstddef>

#define NUSERS 100000
#define BB 16384

typedef __attribute__((ext_vector_type(8))) short bf16x8;
typedef __attribute__((ext_vector_type(4))) float f32x4;

static __device__ __forceinline__ unsigned short f2bf(float x) {
    unsigned u = __float_as_uint(x);
    u += 0x7FFF + ((u >> 16) & 1);          // round-to-nearest-even
    return (unsigned short)(u >> 16);
}
static __device__ __forceinline__ float bf2f(unsigned short h) {
    return __uint_as_float((unsigned)h << 16);
}

// ---------------- K0: per-user G|H table via MFMA + Q scores + RB.
//   GH[u][0:64]  = F[u] @ W1a   (W1a = w1[0:64])    -- "self" transform
//   GH[u][64:128]= F[u] @ W1b   (W1b = w1[64:128])  -- "neigh" transform
// bf16 MFMA (16x16x32), f32 accumulate, f32 store (only w1-rounding added).
// Per block: 64 users, 4 waves; each wave: 16 users x 128 cols, K=64
// -> 16 MFMA. Also computes Q[u] (attention logit) from the staged bf16
// rows, and block 0 computes RB = r_embed @ W1b (5x64, f32 from global w1).
__global__ __launch_bounds__(256) void k0_build(
    const float* __restrict__ features, const float* __restrict__ r_embed,
    const float* __restrict__ wg1, const float* __restrict__ bg1,
    const float* __restrict__ wg2, const float* __restrict__ bg2,
    const float* __restrict__ w1,
    float* __restrict__ Q, float* __restrict__ RB, float* __restrict__ GH)
{
    __shared__ unsigned short Al[64 * 72];   // A bf16 [user][dim], pad 72 (144B rows, 16B-aligned)
    __shared__ unsigned short Bt[128 * 72];  // B^T bf16 [outcol c'][k=d], pad 72
    __shared__ float wg1t[16 * 72];          // wg1 transposed f32 [k][d]

    const int tid = threadIdx.x;
    const int blk = blockIdx.x;
    const int u0  = blk * 64;

    // ---- stage A: 64 users x 64 dims (f32 -> bf16), zero-fill invalid ----
    #pragma unroll
    for (int q = 0; q < 4; ++q) {
        const int idx = tid + q * 256;       // 0..1023
        const int ul  = idx >> 4, qd = idx & 15;
        float4 v = make_float4(0.f, 0.f, 0.f, 0.f);
        if (u0 + ul < NUSERS)
            v = *(const float4*)(features + (size_t)(u0 + ul) * 64 + qd * 4);
        ushort4 o;
        o.x = f2bf(v.x); o.y = f2bf(v.y); o.z = f2bf(v.z); o.w = f2bf(v.w);
        *(ushort4*)&Al[ul * 72 + qd * 4] = o;
    }
    // ---- stage B^T: w1[128][64] -> Bt[c'][d]; c'<64: W1a col, c'>=64: W1b ----
    #pragma unroll
    for (int q = 0; q < 8; ++q) {
        const int idx = tid + q * 256;       // 0..2047
        const int r  = idx >> 4, cq = (idx & 15) * 4;
        const float4 v = *(const float4*)(w1 + r * 64 + cq);
        const int cc = (r < 64) ? cq : (64 + cq);
        const int dd = (r < 64) ? r : (r - 64);
        Bt[(cc + 0) * 72 + dd] = f2bf(v.x);
        Bt[(cc + 1) * 72 + dd] = f2bf(v.y);
        Bt[(cc + 2) * 72 + dd] = f2bf(v.z);
        Bt[(cc + 3) * 72 + dd] = f2bf(v.w);
    }
    // ---- stage wg1 transposed (f32) for the Q-score dot ----
    {
        const float4 w = ((const float4*)wg1)[tid];   // d=tid>>2, k0=(tid&3)*4
        const int d = tid >> 2, k0q = (tid & 3) * 4;
        wg1t[(k0q + 0) * 72 + d] = w.x;
        wg1t[(k0q + 1) * 72 + d] = w.y;
        wg1t[(k0q + 2) * 72 + d] = w.z;
        wg1t[(k0q + 3) * 72 + d] = w.w;
    }
    __syncthreads();

    // ---- MFMA: wave wv owns users wv*16..+15, all 128 cols, K=64 ----
    const int lane = tid & 63, wv = tid >> 6;
    const int arow = wv * 16 + (lane & 15);
    const int hi   = lane >> 4;
    f32x4 acc[8];
    #pragma unroll
    for (int ct = 0; ct < 8; ++ct) acc[ct] = (f32x4){0.f, 0.f, 0.f, 0.f};
    #pragma unroll
    for (int ks = 0; ks < 2; ++ks) {
        // A-frag: row = lane&15 (+wave), k = ks*32 + (lane>>4)*8 + 0..7
        const bf16x8 a = *(const bf16x8*)&Al[arow * 72 + ks * 32 + hi * 8];
        #pragma unroll
        for (int ct = 0; ct < 8; ++ct) {
            // B-frag: col = ct*16 + (lane&15), k = ks*32 + (lane>>4)*8 + 0..7
            const bf16x8 b = *(const bf16x8*)&Bt[(ct * 16 + (lane & 15)) * 72 + ks * 32 + hi * 8];
            acc[ct] = __builtin_amdgcn_mfma_f32_16x16x32_bf16(a, b, acc[ct], 0, 0, 0);
        }
    }
    // ---- store GH: C/D layout col=lane&15, row=(lane>>4)*4+reg [m89] ----
    #pragma unroll
    for (int ct = 0; ct < 8; ++ct) {
        #pragma unroll
        for (int j = 0; j < 4; ++j) {
            const int ul = wv * 16 + hi * 4 + j;
            const int u  = u0 + ul;
            if (u < NUSERS)
                GH[(size_t)u * 128 + ct * 16 + (lane & 15)] = acc[ct][j];
        }
    }

    // ---- Q scores from staged bf16 rows (thread: k=tid&15, 4 users) ----
    {
        const int k = tid & 15, ug = tid >> 4;
        const float bg1v = bg1[k], wk2 = wg2[k], bg2v = bg2[0];
        #pragma unroll
        for (int un = 0; un < 4; ++un) {
            const int ul = ug + un * 16;
            float x = bg1v;
            #pragma unroll
            for (int d8 = 0; d8 < 8; ++d8) {
                const ushort4 pa = *(const ushort4*)&Al[ul * 72 + d8 * 8];
                const ushort4 pb = *(const ushort4*)&Al[ul * 72 + d8 * 8 + 4];
                x += bf2f(pa.x) * wg1t[k * 72 + d8 * 8 + 0]
                   + bf2f(pa.y) * wg1t[k * 72 + d8 * 8 + 1]
                   + bf2f(pa.z) * wg1t[k * 72 + d8 * 8 + 2]
                   + bf2f(pa.w) * wg1t[k * 72 + d8 * 8 + 3]
                   + bf2f(pb.x) * wg1t[k * 72 + d8 * 8 + 4]
                   + bf2f(pb.y) * wg1t[k * 72 + d8 * 8 + 5]
                   + bf2f(pb.z) * wg1t[k * 72 + d8 * 8 + 6]
                   + bf2f(pb.w) * wg1t[k * 72 + d8 * 8 + 7];
            }
            float xx = fminf(fmaxf(x, -9.f), 9.f);
            float e2 = __expf(2.f * xx);
            float th = (e2 - 1.f) / (e2 + 1.f);
            float t = th * wk2;
            t += __shfl_xor(t, 1);
            t += __shfl_xor(t, 2);
            t += __shfl_xor(t, 4);
            t += __shfl_xor(t, 8);
            if (k == 0 && u0 + ul < NUSERS) Q[u0 + ul] = t + bg2v;
        }
    }

    // ---- RB = r_embed @ W1b (block 0 only; coalesced over c) ----
    if (blk == 0) {
        for (int t = tid; t < 320; t += 256) {
            const int r = t >> 6, c = t & 63;
            float a = 0.f;
            #pragma unroll 8
            for (int d = 0; d < 64; ++d)
                a += r_embed[r * 64 + d] * w1[(64 + d) * 64 + c];
            RB[r * 64 + c] = a;
        }
    }
}

// ---------------- K1: lean gather-accumulate against the f32 G|H table.
// Round-12 PMC (k1 finally visible): occupancy 72% (healthy), VALUBusy 41%
// ~= the 27us warm structural cost -> VALU/issue-bound; the matvec tail
// (~220 instrs/wave incl. 32 w1 VMEM) was the largest block. It is GONE:
// members gather G rows (already W1a-transformed), neighbors gather H rows
// (W1b-transformed), output = relu(sf + nb + rc + b1) directly. f32 gathers
// also remove all bf16-unpack VALU. Gather count/structure unchanged.
__global__ __launch_bounds__(256) void k1_fuse(
    const int* __restrict__ nodes, const int* __restrict__ hist_u,
    const int* __restrict__ hist_r, const int* __restrict__ hist_m,
    const int* __restrict__ soc_a, const int* __restrict__ soc_m,
    const float* __restrict__ GH, const float* __restrict__ RB,
    const float* __restrict__ Q, const float* __restrict__ b1,
    float* __restrict__ out)
{
    __shared__ int lcomp[4][96];      // 1536B: merged byte-offset list per wave

    const int tid  = threadIdx.x;
    const int lane = tid & 63;
    const int wv   = tid >> 6;
    const int e    = blockIdx.x * 4 + wv;
    const int sub  = lane & 15;       // dim quad
    const int grp  = lane >> 4;       // row slot
    const char* fb = (const char*)GH; // row-pair stride 512B: G at +0, H at +256

    int* lc = lcomp[wv];

    // ---- zero-init merged list (tail: offset 0 = G row of user 0, w=0) ----
    lc[lane] = 0;
    if (lane < 32) lc[64 + lane] = 0;

    // ---- index loads (issue ASAP) ----
    int nd = (lane < 8) ? nodes[e * 8 + lane] : 0;
    int hu = 0, hr = 0, hmv = 0;
    if (lane < 50) {
        hu  = hist_u[e * 50 + lane];
        hr  = hist_r[e * 50 + lane];
        hmv = hist_m[e * 50 + lane];
    }
    int sa = 0, sk = 0;
    if (lane < 32) {
        sa = soc_a[e * 32 + lane];
        sk = soc_m[e * 32 + lane];
    }

    // ---- ballots / counts ----
    uint64_t hb = __ballot(hmv != 0);
    const int hc = (int)__popcll(hb);
    int hrank = (int)__popcll(hb & ((1ull << lane) - 1));

    uint64_t sbm = __ballot(sk != 0);
    const int scn = (int)__popcll(sbm);
    int srank = (int)__popcll(sbm & ((1ull << lane) - 1));

    const float hw = 0.5f / (float)hc;     // hc >= 1 (mask[:,0]=True)
    const float sw = 0.5f / (float)scn;    // scn >= 1
    const int   n  = hc + scn;             // <= 82

    // ---- merged compaction: neighbor offsets point at the H half ----
    if (hmv) lc[hrank] = (hu << 9) + 256;
    if (sk)  lc[hc + srank] = (sa << 9) + 256;

    // ---- rating counts ----
    const int c0 = (int)__popcll(__ballot(hmv && hr == 0));
    const int c1 = (int)__popcll(__ballot(hmv && hr == 1));
    const int c2 = (int)__popcll(__ballot(hmv && hr == 2));
    const int c3 = (int)__popcll(__ballot(hmv && hr == 3));
    const int c4 = (int)__popcll(__ballot(hmv && hr == 4));

    // ---- read back merged list ----
    int pkA = lc[lane];
    int pkB = lc[64 + (lane & 31)];

    // ---- softmax over 8 group logits from precomputed Q (lanes 0..7) ----
    float sc = (lane < 8) ? Q[nd] : -1e30f;
    float mx = sc;
    mx = fmaxf(mx, __shfl_xor(mx, 1));
    mx = fmaxf(mx, __shfl_xor(mx, 2));
    mx = fmaxf(mx, __shfl_xor(mx, 4));
    float ex = __expf(sc - mx);
    float sm = ex;
    sm += __shfl_xor(sm, 1);
    sm += __shfl_xor(sm, 2);
    sm += __shfl_xor(sm, 4);
    float al = ex / sm;                 // valid on lanes 0..7

    // ---- member gathers: G rows (8 rows; 2 float4 per lane), alpha-weighted ----
    float4 sf4;
    {
        const float a0 = __shfl(al, grp);
        const int   u0 = __shfl(nd, grp);
        const float a1 = __shfl(al, 4 + grp);
        const int   u1 = __shfl(nd, 4 + grp);
        const float4 v0 = *(const float4*)(fb + ((unsigned)u0 << 9) + sub * 16);
        const float4 v1 = *(const float4*)(fb + ((unsigned)u1 << 9) + sub * 16);
        sf4.x = a0 * v0.x + a1 * v1.x;
        sf4.y = a0 * v0.y + a1 * v1.y;
        sf4.z = a0 * v0.z + a1 * v1.z;
        sf4.w = a0 * v0.w + a1 * v1.w;
    }

    // ---- merged neighbor gathers: H rows, 16 rows (4 loads) per iter ----
    float4 nb4 = {0.f, 0.f, 0.f, 0.f};
    for (int base = 0; base < n; base += 16) {
        #pragma unroll
        for (int j = 0; j < 4; ++j) {
            const int cbase = base + j * 4;       // uniform, 4-aligned
            int off;
            if (cbase < 64) off = __shfl(pkA, cbase + grp);
            else            off = __shfl(pkB, cbase - 64 + grp);
            const int idx = cbase + grp;
            const float w = (idx < hc) ? hw : ((idx < n) ? sw : 0.f);
            const float4 v = *(const float4*)(fb + (unsigned)off + sub * 16);
            nb4.x += w * v.x; nb4.y += w * v.y;
            nb4.z += w * v.z; nb4.w += w * v.w;
        }
    }

    // ---- cross-group reduction ----
#define XRED(v4)                                            \
    v4.x += __shfl_xor(v4.x, 16); v4.x += __shfl_xor(v4.x, 32); \
    v4.y += __shfl_xor(v4.y, 16); v4.y += __shfl_xor(v4.y, 32); \
    v4.z += __shfl_xor(v4.z, 16); v4.z += __shfl_xor(v4.z, 32); \
    v4.w += __shfl_xor(v4.w, 16); v4.w += __shfl_xor(v4.w, 32);
    XRED(sf4)
    XRED(nb4)
#undef XRED

    // ---- rating-count correction via RB = r_embed@W1b ----
    {
        const float4* rb4 = (const float4*)RB;
        const float4 r0 = rb4[0 * 16 + sub];
        const float4 r1 = rb4[1 * 16 + sub];
        const float4 r2 = rb4[2 * 16 + sub];
        const float4 r3 = rb4[3 * 16 + sub];
        const float4 r4 = rb4[4 * 16 + sub];
        const float f0 = hw * (float)c0, f1 = hw * (float)c1, f2 = hw * (float)c2,
                    f3 = hw * (float)c3, f4 = hw * (float)c4;
        nb4.x += f0 * r0.x + f1 * r1.x + f2 * r2.x + f3 * r3.x + f4 * r4.x;
        nb4.y += f0 * r0.y + f1 * r1.y + f2 * r2.y + f3 * r3.y + f4 * r4.y;
        nb4.z += f0 * r0.z + f1 * r1.z + f2 * r2.z + f3 * r3.z + f4 * r4.z;
        nb4.w += f0 * r0.w + f1 * r1.w + f2 * r2.w + f3 * r3.w + f4 * r4.w;
    }

    // ---- output: relu(self + neigh + b1), direct store ----
    if (grp == 0) {
        const float4 bv = *(const float4*)(b1 + sub * 4);
        float4 o;
        o.x = fmaxf(sf4.x + nb4.x + bv.x, 0.f);
        o.y = fmaxf(sf4.y + nb4.y + bv.y, 0.f);
        o.z = fmaxf(sf4.z + nb4.z + bv.z, 0.f);
        o.w = fmaxf(sf4.w + nb4.w + bv.w, 0.f);
        *(float4*)(out + (size_t)e * 64 + sub * 4) = o;
    }
}

extern "C" void kernel_launch(void* const* d_in, const int* in_sizes, int n_in,
                              void* d_out, int out_size, void* d_ws, size_t ws_size,
                              hipStream_t stream)
{
    const int*   nodes    = (const int*)d_in[0];
    const int*   hu       = (const int*)d_in[1];
    const int*   hr       = (const int*)d_in[2];
    const int*   hm       = (const int*)d_in[3];
    const int*   sa       = (const int*)d_in[4];
    const int*   smk      = (const int*)d_in[5];
    const float* features = (const float*)d_in[6];
    const float* r_embed  = (const float*)d_in[7];
    const float* wg1      = (const float*)d_in[8];
    const float* bg1      = (const float*)d_in[9];
    const float* wg2      = (const float*)d_in[10];
    const float* bg2      = (const float*)d_in[11];
    const float* w1       = (const float*)d_in[12];
    const float* b1       = (const float*)d_in[13];
    float* out = (float*)d_out;

    // ws layout (~51.8 MB; fills prove ws ~= 256 MB):
    float* Q  = (float*)d_ws;            // 131072 floats reserved
    float* RB = Q + 131072;              // 512 floats reserved (320 used)
    float* GH = RB + 512;                // 100000 * 128 f32 = 51.2 MB

    k0_build<<<(NUSERS + 63) / 64, 256, 0, stream>>>(
        features, r_embed, wg1, bg1, wg2, bg2, w1, Q, RB, GH);
    k1_fuse<<<BB / 4, 256, 0, stream>>>(nodes, hu, hr, hm, sa, smk,
                                        GH, RB, Q, b1, out);
}

// Round 14
// 142.457 us; speedup vs baseline: 1.1699x; 1.0524x over previous
//
#include <hip/hip_runtime.h>
#include <hip/hip_fp16.h>
#include <cstdint>
#include <cstddef>

#define NUSERS 100000
#define BB 16384

typedef __attribute__((ext_vector_type(8))) _Float16 f16x8;
typedef __attribute__((ext_vector_type(4))) float f32x4;

static __device__ __forceinline__ unsigned short f2h(float x) {
    __half h = __float2half_rn(x);
    return *reinterpret_cast<unsigned short*>(&h);
}
static __device__ __forceinline__ float h2f(unsigned short u) {
    __half h = *reinterpret_cast<__half*>(&u);
    return __half2float(h);
}
static __device__ __forceinline__ float4 hf4_to_f4(ushort4 h) {
    float4 r;
    r.x = h2f(h.x); r.y = h2f(h.y); r.z = h2f(h.z); r.w = h2f(h.w);
    return r;
}

// ---------------- K0: f16 G|H table via MFMA + Q scores + RB.
//   GH[u][0:64]  = F[u] @ W1a  (f16 store)   GH[u][64:128] = F[u] @ W1b
// f16 everywhere in the GEMM (features ~N(0,0.02): f16 rounding ~10x finer
// than the bf16 used in rounds 7-13 -> absmax should IMPROVE).
// Fragment geometry identical to round-13's pass (HW-verified); only dtype
// changed. RB = r_embed @ W1b computed exactly in f32 (block 0).
__global__ __launch_bounds__(256) void k0_build(
    const float* __restrict__ features, const float* __restrict__ r_embed,
    const float* __restrict__ wg1, const float* __restrict__ bg1,
    const float* __restrict__ wg2, const float* __restrict__ bg2,
    const float* __restrict__ w1,
    float* __restrict__ Q, float* __restrict__ RB,
    unsigned short* __restrict__ GH)
{
    __shared__ unsigned short Al[64 * 72];   // A f16 [user][dim], pad 72 (144B rows)
    __shared__ unsigned short Bt[128 * 72];  // B^T f16 [outcol c'][k=d], pad 72
    __shared__ float wg1t[16 * 72];          // wg1 transposed f32 [k][d]

    const int tid = threadIdx.x;
    const int blk = blockIdx.x;
    const int u0  = blk * 64;

    // ---- stage A: 64 users x 64 dims (f32 -> f16), zero-fill invalid ----
    #pragma unroll
    for (int q = 0; q < 4; ++q) {
        const int idx = tid + q * 256;       // 0..1023
        const int ul  = idx >> 4, qd = idx & 15;
        float4 v = make_float4(0.f, 0.f, 0.f, 0.f);
        if (u0 + ul < NUSERS)
            v = *(const float4*)(features + (size_t)(u0 + ul) * 64 + qd * 4);
        ushort4 o;
        o.x = f2h(v.x); o.y = f2h(v.y); o.z = f2h(v.z); o.w = f2h(v.w);
        *(ushort4*)&Al[ul * 72 + qd * 4] = o;
    }
    // ---- stage B^T: w1[128][64] -> Bt[c'][d]; c'<64: W1a col, c'>=64: W1b ----
    #pragma unroll
    for (int q = 0; q < 8; ++q) {
        const int idx = tid + q * 256;       // 0..2047
        const int r  = idx >> 4, cq = (idx & 15) * 4;
        const float4 v = *(const float4*)(w1 + r * 64 + cq);
        const int cc = (r < 64) ? cq : (64 + cq);
        const int dd = (r < 64) ? r : (r - 64);
        Bt[(cc + 0) * 72 + dd] = f2h(v.x);
        Bt[(cc + 1) * 72 + dd] = f2h(v.y);
        Bt[(cc + 2) * 72 + dd] = f2h(v.z);
        Bt[(cc + 3) * 72 + dd] = f2h(v.w);
    }
    // ---- stage wg1 transposed (f32) for the Q-score dot ----
    {
        const float4 w = ((const float4*)wg1)[tid];   // d=tid>>2, k0=(tid&3)*4
        const int d = tid >> 2, k0q = (tid & 3) * 4;
        wg1t[(k0q + 0) * 72 + d] = w.x;
        wg1t[(k0q + 1) * 72 + d] = w.y;
        wg1t[(k0q + 2) * 72 + d] = w.z;
        wg1t[(k0q + 3) * 72 + d] = w.w;
    }
    __syncthreads();

    // ---- MFMA: wave wv owns users wv*16..+15, all 128 cols, K=64 ----
    const int lane = tid & 63, wv = tid >> 6;
    const int arow = wv * 16 + (lane & 15);
    const int hi   = lane >> 4;
    f32x4 acc[8];
    #pragma unroll
    for (int ct = 0; ct < 8; ++ct) acc[ct] = (f32x4){0.f, 0.f, 0.f, 0.f};
    #pragma unroll
    for (int ks = 0; ks < 2; ++ks) {
        const f16x8 a = *(const f16x8*)&Al[arow * 72 + ks * 32 + hi * 8];
        #pragma unroll
        for (int ct = 0; ct < 8; ++ct) {
            const f16x8 b = *(const f16x8*)&Bt[(ct * 16 + (lane & 15)) * 72 + ks * 32 + hi * 8];
            acc[ct] = __builtin_amdgcn_mfma_f32_16x16x32_f16(a, b, acc[ct], 0, 0, 0);
        }
    }
    // ---- store GH as f16, lane-pair packed u32 (cols 2m|2m+1) ----
    // C/D layout: col = ct*16 + (lane&15), row = wv*16 + hi*4 + j  [m89]
    #pragma unroll
    for (int ct = 0; ct < 8; ++ct) {
        #pragma unroll
        for (int j = 0; j < 4; ++j) {
            const float own  = acc[ct][j];
            const float part = __shfl_xor(own, 1);   // col c^1
            const int u = u0 + wv * 16 + hi * 4 + j;
            if (((lane & 1) == 0) && u < NUSERS) {
                const int c = ct * 16 + (lane & 15);         // even
                const unsigned val = (unsigned)f2h(own) | ((unsigned)f2h(part) << 16);
                *(unsigned*)(GH + (size_t)u * 128 + c) = val;
            }
        }
    }

    // ---- Q scores from staged f16 rows (thread: k=tid&15, 4 users) ----
    {
        const int k = tid & 15, ug = tid >> 4;
        const float bg1v = bg1[k], wk2 = wg2[k], bg2v = bg2[0];
        #pragma unroll
        for (int un = 0; un < 4; ++un) {
            const int ul = ug + un * 16;
            float x = bg1v;
            #pragma unroll
            for (int d8 = 0; d8 < 8; ++d8) {
                const ushort4 pa = *(const ushort4*)&Al[ul * 72 + d8 * 8];
                const ushort4 pb = *(const ushort4*)&Al[ul * 72 + d8 * 8 + 4];
                x += h2f(pa.x) * wg1t[k * 72 + d8 * 8 + 0]
                   + h2f(pa.y) * wg1t[k * 72 + d8 * 8 + 1]
                   + h2f(pa.z) * wg1t[k * 72 + d8 * 8 + 2]
                   + h2f(pa.w) * wg1t[k * 72 + d8 * 8 + 3]
                   + h2f(pb.x) * wg1t[k * 72 + d8 * 8 + 4]
                   + h2f(pb.y) * wg1t[k * 72 + d8 * 8 + 5]
                   + h2f(pb.z) * wg1t[k * 72 + d8 * 8 + 6]
                   + h2f(pb.w) * wg1t[k * 72 + d8 * 8 + 7];
            }
            float xx = fminf(fmaxf(x, -9.f), 9.f);
            float e2 = __expf(2.f * xx);
            float th = (e2 - 1.f) / (e2 + 1.f);
            float t = th * wk2;
            t += __shfl_xor(t, 1);
            t += __shfl_xor(t, 2);
            t += __shfl_xor(t, 4);
            t += __shfl_xor(t, 8);
            if (k == 0 && u0 + ul < NUSERS) Q[u0 + ul] = t + bg2v;
        }
    }

    // ---- RB = r_embed @ W1b (block 0 only; exact f32) ----
    if (blk == 0) {
        for (int t = tid; t < 320; t += 256) {
            const int r = t >> 6, c = t & 63;
            float a = 0.f;
            #pragma unroll 8
            for (int d = 0; d < 64; ++d)
                a += r_embed[r * 64 + d] * w1[(64 + d) * 64 + c];
            RB[r * 64 + c] = a;
        }
    }
}

// ---------------- K1: lean gather-accumulate against the f16 G|H table.
// Same gather engine as round 7 (128B rows, 8 cache lines per 4-row gather
// instruction, 104 lines/element) but ZERO matvec tail (-128 line-visits,
// -190 instrs/wave vs round 7). Output = relu(sf + nb + rc + b1).
__global__ __launch_bounds__(256) void k1_fuse(
    const int* __restrict__ nodes, const int* __restrict__ hist_u,
    const int* __restrict__ hist_r, const int* __restrict__ hist_m,
    const int* __restrict__ soc_a, const int* __restrict__ soc_m,
    const unsigned short* __restrict__ GH, const float* __restrict__ RB,
    const float* __restrict__ Q, const float* __restrict__ b1,
    float* __restrict__ out)
{
    __shared__ int lcomp[4][96];      // 1536B: merged byte-offset list per wave

    const int tid  = threadIdx.x;
    const int lane = tid & 63;
    const int wv   = tid >> 6;
    const int e    = blockIdx.x * 4 + wv;
    const int sub  = lane & 15;       // dim quad
    const int grp  = lane >> 4;       // row slot
    const char* fb = (const char*)GH; // row-pair stride 256B: G at +0, H at +128

    int* lc = lcomp[wv];

    // ---- zero-init merged list (tail: offset 0 = G row of user 0, w=0) ----
    lc[lane] = 0;
    if (lane < 32) lc[64 + lane] = 0;

    // ---- index loads (issue ASAP) ----
    int nd = (lane < 8) ? nodes[e * 8 + lane] : 0;
    int hu = 0, hr = 0, hmv = 0;
    if (lane < 50) {
        hu  = hist_u[e * 50 + lane];
        hr  = hist_r[e * 50 + lane];
        hmv = hist_m[e * 50 + lane];
    }
    int sa = 0, sk = 0;
    if (lane < 32) {
        sa = soc_a[e * 32 + lane];
        sk = soc_m[e * 32 + lane];
    }

    // ---- ballots / counts ----
    uint64_t hb = __ballot(hmv != 0);
    const int hc = (int)__popcll(hb);
    int hrank = (int)__popcll(hb & ((1ull << lane) - 1));

    uint64_t sbm = __ballot(sk != 0);
    const int scn = (int)__popcll(sbm);
    int srank = (int)__popcll(sbm & ((1ull << lane) - 1));

    const float hw = 0.5f / (float)hc;     // hc >= 1 (mask[:,0]=True)
    const float sw = 0.5f / (float)scn;    // scn >= 1
    const int   n  = hc + scn;             // <= 82

    // ---- merged compaction: neighbor offsets point at the H half ----
    if (hmv) lc[hrank] = (hu << 8) + 128;
    if (sk)  lc[hc + srank] = (sa << 8) + 128;

    // ---- rating counts ----
    const int c0 = (int)__popcll(__ballot(hmv && hr == 0));
    const int c1 = (int)__popcll(__ballot(hmv && hr == 1));
    const int c2 = (int)__popcll(__ballot(hmv && hr == 2));
    const int c3 = (int)__popcll(__ballot(hmv && hr == 3));
    const int c4 = (int)__popcll(__ballot(hmv && hr == 4));

    // ---- read back merged list ----
    int pkA = lc[lane];
    int pkB = lc[64 + (lane & 31)];

    // ---- softmax over 8 group logits from precomputed Q (lanes 0..7) ----
    float sc = (lane < 8) ? Q[nd] : -1e30f;
    float mx = sc;
    mx = fmaxf(mx, __shfl_xor(mx, 1));
    mx = fmaxf(mx, __shfl_xor(mx, 2));
    mx = fmaxf(mx, __shfl_xor(mx, 4));
    float ex = __expf(sc - mx);
    float sm = ex;
    sm += __shfl_xor(sm, 1);
    sm += __shfl_xor(sm, 2);
    sm += __shfl_xor(sm, 4);
    float al = ex / sm;                 // valid on lanes 0..7

    // ---- member gathers: G rows (8 rows; 2 ushort4 per lane), alpha-weighted ----
    float4 sf4;
    {
        const float a0 = __shfl(al, grp);
        const int   u0 = __shfl(nd, grp);
        const float a1 = __shfl(al, 4 + grp);
        const int   u1 = __shfl(nd, 4 + grp);
        const float4 v0 = hf4_to_f4(*(const ushort4*)(fb + ((unsigned)u0 << 8) + sub * 8));
        const float4 v1 = hf4_to_f4(*(const ushort4*)(fb + ((unsigned)u1 << 8) + sub * 8));
        sf4.x = a0 * v0.x + a1 * v1.x;
        sf4.y = a0 * v0.y + a1 * v1.y;
        sf4.z = a0 * v0.z + a1 * v1.z;
        sf4.w = a0 * v0.w + a1 * v1.w;
    }

    // ---- merged neighbor gathers: H rows, 16 rows (4 loads) per iter ----
    float4 nb4 = {0.f, 0.f, 0.f, 0.f};
    for (int base = 0; base < n; base += 16) {
        #pragma unroll
        for (int j = 0; j < 4; ++j) {
            const int cbase = base + j * 4;       // uniform, 4-aligned
            int off;
            if (cbase < 64) off = __shfl(pkA, cbase + grp);
            else            off = __shfl(pkB, cbase - 64 + grp);
            const int idx = cbase + grp;
            const float w = (idx < hc) ? hw : ((idx < n) ? sw : 0.f);
            const float4 v = hf4_to_f4(*(const ushort4*)(fb + (unsigned)off + sub * 8));
            nb4.x += w * v.x; nb4.y += w * v.y;
            nb4.z += w * v.z; nb4.w += w * v.w;
        }
    }

    // ---- cross-group reduction ----
#define XRED(v4)                                            \
    v4.x += __shfl_xor(v4.x, 16); v4.x += __shfl_xor(v4.x, 32); \
    v4.y += __shfl_xor(v4.y, 16); v4.y += __shfl_xor(v4.y, 32); \
    v4.z += __shfl_xor(v4.z, 16); v4.z += __shfl_xor(v4.z, 32); \
    v4.w += __shfl_xor(v4.w, 16); v4.w += __shfl_xor(v4.w, 32);
    XRED(sf4)
    XRED(nb4)
#undef XRED

    // ---- rating-count correction via RB = r_embed@W1b (exact f32) ----
    {
        const float4* rb4 = (const float4*)RB;
        const float4 r0 = rb4[0 * 16 + sub];
        const float4 r1 = rb4[1 * 16 + sub];
        const float4 r2 = rb4[2 * 16 + sub];
        const float4 r3 = rb4[3 * 16 + sub];
        const float4 r4 = rb4[4 * 16 + sub];
        const float f0 = hw * (float)c0, f1 = hw * (float)c1, f2 = hw * (float)c2,
                    f3 = hw * (float)c3, f4 = hw * (float)c4;
        nb4.x += f0 * r0.x + f1 * r1.x + f2 * r2.x + f3 * r3.x + f4 * r4.x;
        nb4.y += f0 * r0.y + f1 * r1.y + f2 * r2.y + f3 * r3.y + f4 * r4.y;
        nb4.z += f0 * r0.z + f1 * r1.z + f2 * r2.z + f3 * r3.z + f4 * r4.z;
        nb4.w += f0 * r0.w + f1 * r1.w + f2 * r2.w + f3 * r3.w + f4 * r4.w;
    }

    // ---- output: relu(self + neigh + b1), direct store ----
    if (grp == 0) {
        const float4 bv = *(const float4*)(b1 + sub * 4);
        float4 o;
        o.x = fmaxf(sf4.x + nb4.x + bv.x, 0.f);
        o.y = fmaxf(sf4.y + nb4.y + bv.y, 0.f);
        o.z = fmaxf(sf4.z + nb4.z + bv.z, 0.f);
        o.w = fmaxf(sf4.w + nb4.w + bv.w, 0.f);
        *(float4*)(out + (size_t)e * 64 + sub * 4) = o;
    }
}

extern "C" void kernel_launch(void* const* d_in, const int* in_sizes, int n_in,
                              void* d_out, int out_size, void* d_ws, size_t ws_size,
                              hipStream_t stream)
{
    const int*   nodes    = (const int*)d_in[0];
    const int*   hu       = (const int*)d_in[1];
    const int*   hr       = (const int*)d_in[2];
    const int*   hm       = (const int*)d_in[3];
    const int*   sa       = (const int*)d_in[4];
    const int*   smk      = (const int*)d_in[5];
    const float* features = (const float*)d_in[6];
    const float* r_embed  = (const float*)d_in[7];
    const float* wg1      = (const float*)d_in[8];
    const float* bg1      = (const float*)d_in[9];
    const float* wg2      = (const float*)d_in[10];
    const float* bg2      = (const float*)d_in[11];
    const float* w1       = (const float*)d_in[12];
    const float* b1       = (const float*)d_in[13];
    float* out = (float*)d_out;

    // ws layout (~26.2 MB):
    float*          Q  = (float*)d_ws;       // 131072 floats reserved
    float*          RB = Q + 131072;         // 512 floats reserved (320 used)
    unsigned short* GH = (unsigned short*)(RB + 512);   // 100000*128 f16 = 25.6 MB

    k0_build<<<(NUSERS + 63) / 64, 256, 0, stream>>>(
        features, r_embed, wg1, bg1, wg2, bg2, w1, Q, RB, GH);
    k1_fuse<<<BB / 4, 256, 0, stream>>>(nodes, hu, hr, hm, sa, smk,
                                        GH, RB, Q, b1, out);
}

// Round 16
// 136.484 us; speedup vs baseline: 1.2211x; 1.0438x over previous
//
#include <hip/hip_runtime.h>
#include <hip/hip_fp16.h>
#include <cstdint>
#include <cstddef>

#define NUSERS 100000
#define BB 16384

typedef __attribute__((ext_vector_type(8))) _Float16 f16x8;
typedef __attribute__((ext_vector_type(4))) float f32x4;

static __device__ __forceinline__ unsigned short f2h(float x) {
    __half h = __float2half_rn(x);
    return *reinterpret_cast<unsigned short*>(&h);
}
static __device__ __forceinline__ float h2f(unsigned short u) {
    __half h = *reinterpret_cast<__half*>(&u);
    return __half2float(h);
}
static __device__ __forceinline__ float4 hf4_to_f4(ushort4 h) {
    float4 r;
    r.x = h2f(h.x); r.y = h2f(h.y); r.z = h2f(h.z); r.w = h2f(h.w);
    return r;
}

// ---------------- K0 v2 (resubmit of round-15 source; round-15 bench died
// to a container-acquisition failure, as round 3 did): f16 G|H table +
// Q scores, BOTH via MFMA.
// Round-14's k0 had a ~300-VALU scalar Q pass per thread; replaced by a
// second MFMA tile (S = F @ wg1, 64x16, K=64 -> 2 MFMA/wave) reusing the
// staged A fragments. GH GEMM unchanged (m89-verified fragment geometry,
// passing since round 13). Traffic floor ~51MB ~= 8us.
__global__ __launch_bounds__(256) void k0_build(
    const float* __restrict__ features, const float* __restrict__ r_embed,
    const float* __restrict__ wg1, const float* __restrict__ bg1,
    const float* __restrict__ wg2, const float* __restrict__ bg2,
    const float* __restrict__ w1,
    float* __restrict__ Q, float* __restrict__ RB,
    unsigned short* __restrict__ GH)
{
    __shared__ unsigned short Al[64 * 72];   // A f16 [user][dim], pad 72
    __shared__ unsigned short Bt[128 * 72];  // w1^T f16 [outcol c'][k=d], pad 72
    __shared__ unsigned short Wg[16 * 72];   // wg1^T f16 [att_k][d], pad 72

    const int tid = threadIdx.x;
    const int blk = blockIdx.x;
    const int u0  = blk * 64;

    // ---- stage A: 64 users x 64 dims (f32 -> f16), zero-fill invalid ----
    #pragma unroll
    for (int q = 0; q < 4; ++q) {
        const int idx = tid + q * 256;       // 0..1023
        const int ul  = idx >> 4, qd = idx & 15;
        float4 v = make_float4(0.f, 0.f, 0.f, 0.f);
        if (u0 + ul < NUSERS)
            v = *(const float4*)(features + (size_t)(u0 + ul) * 64 + qd * 4);
        ushort4 o;
        o.x = f2h(v.x); o.y = f2h(v.y); o.z = f2h(v.z); o.w = f2h(v.w);
        *(ushort4*)&Al[ul * 72 + qd * 4] = o;
    }
    // ---- stage B^T: w1[128][64] -> Bt[c'][d]; c'<64: W1a col, c'>=64: W1b ----
    #pragma unroll
    for (int q = 0; q < 8; ++q) {
        const int idx = tid + q * 256;       // 0..2047
        const int r  = idx >> 4, cq = (idx & 15) * 4;
        const float4 v = *(const float4*)(w1 + r * 64 + cq);
        const int cc = (r < 64) ? cq : (64 + cq);
        const int dd = (r < 64) ? r : (r - 64);
        Bt[(cc + 0) * 72 + dd] = f2h(v.x);
        Bt[(cc + 1) * 72 + dd] = f2h(v.y);
        Bt[(cc + 2) * 72 + dd] = f2h(v.z);
        Bt[(cc + 3) * 72 + dd] = f2h(v.w);
    }
    // ---- stage wg1^T as f16 for the Q MFMA ----
    {
        const float4 w = ((const float4*)wg1)[tid];   // d=tid>>2, k0=(tid&3)*4
        const int d = tid >> 2, kq = (tid & 3) * 4;
        Wg[(kq + 0) * 72 + d] = f2h(w.x);
        Wg[(kq + 1) * 72 + d] = f2h(w.y);
        Wg[(kq + 2) * 72 + d] = f2h(w.z);
        Wg[(kq + 3) * 72 + d] = f2h(w.w);
    }
    __syncthreads();

    // ---- MFMA 1: GH — wave wv owns users wv*16..+15, 128 cols, K=64 ----
    const int lane = tid & 63, wv = tid >> 6;
    const int arow = wv * 16 + (lane & 15);
    const int hi   = lane >> 4;
    f32x4 acc[8];
    #pragma unroll
    for (int ct = 0; ct < 8; ++ct) acc[ct] = (f32x4){0.f, 0.f, 0.f, 0.f};
    f32x4 qacc = (f32x4){0.f, 0.f, 0.f, 0.f};
    #pragma unroll
    for (int ks = 0; ks < 2; ++ks) {
        const f16x8 a = *(const f16x8*)&Al[arow * 72 + ks * 32 + hi * 8];
        #pragma unroll
        for (int ct = 0; ct < 8; ++ct) {
            const f16x8 b = *(const f16x8*)&Bt[(ct * 16 + (lane & 15)) * 72 + ks * 32 + hi * 8];
            acc[ct] = __builtin_amdgcn_mfma_f32_16x16x32_f16(a, b, acc[ct], 0, 0, 0);
        }
        // ---- MFMA 2: Q logits — S = F @ wg1 (16 att cols) ----
        const f16x8 bq = *(const f16x8*)&Wg[(lane & 15) * 72 + ks * 32 + hi * 8];
        qacc = __builtin_amdgcn_mfma_f32_16x16x32_f16(a, bq, qacc, 0, 0, 0);
    }

    // ---- store GH as f16, lane-pair packed u32 (cols 2m|2m+1) ----
    #pragma unroll
    for (int ct = 0; ct < 8; ++ct) {
        #pragma unroll
        for (int j = 0; j < 4; ++j) {
            const float own  = acc[ct][j];
            const float part = __shfl_xor(own, 1);   // col c^1
            const int u = u0 + wv * 16 + hi * 4 + j;
            if (((lane & 1) == 0) && u < NUSERS) {
                const int c = ct * 16 + (lane & 15);         // even
                const unsigned val = (unsigned)f2h(own) | ((unsigned)f2h(part) << 16);
                *(unsigned*)(GH + (size_t)u * 128 + c) = val;
            }
        }
    }

    // ---- Q: tanh(S + bg1) * wg2, reduce over the 16 att cols ----
    // C layout: col = lane&15 = att k; row = wv*16 + hi*4 + j  [m89]
    {
        const float bg1v = bg1[lane & 15];
        const float wk2  = wg2[lane & 15];
        const float bg2v = bg2[0];
        #pragma unroll
        for (int j = 0; j < 4; ++j) {
            const float s = qacc[j] + bg1v;
            const float xx = fminf(fmaxf(s, -9.f), 9.f);
            const float e2 = __expf(2.f * xx);
            float t = (e2 - 1.f) / (e2 + 1.f) * wk2;
            t += __shfl_xor(t, 1);
            t += __shfl_xor(t, 2);
            t += __shfl_xor(t, 4);
            t += __shfl_xor(t, 8);
            const int u = u0 + wv * 16 + hi * 4 + j;
            if (((lane & 15) == 0) && u < NUSERS) Q[u] = t + bg2v;
        }
    }

    // ---- RB = r_embed @ W1b (block 0 only; exact f32) ----
    if (blk == 0) {
        for (int t = tid; t < 320; t += 256) {
            const int r = t >> 6, c = t & 63;
            float a = 0.f;
            #pragma unroll 8
            for (int d = 0; d < 64; ++d)
                a += r_embed[r * 64 + d] * w1[(64 + d) * 64 + c];
            RB[r * 64 + c] = a;
        }
    }
}

// ---------------- K1: byte-identical to round 14 (lean gather, no matvec).
__global__ __launch_bounds__(256) void k1_fuse(
    const int* __restrict__ nodes, const int* __restrict__ hist_u,
    const int* __restrict__ hist_r, const int* __restrict__ hist_m,
    const int* __restrict__ soc_a, const int* __restrict__ soc_m,
    const unsigned short* __restrict__ GH, const float* __restrict__ RB,
    const float* __restrict__ Q, const float* __restrict__ b1,
    float* __restrict__ out)
{
    __shared__ int lcomp[4][96];      // 1536B: merged byte-offset list per wave

    const int tid  = threadIdx.x;
    const int lane = tid & 63;
    const int wv   = tid >> 6;
    const int e    = blockIdx.x * 4 + wv;
    const int sub  = lane & 15;       // dim quad
    const int grp  = lane >> 4;       // row slot
    const char* fb = (const char*)GH; // row-pair stride 256B: G at +0, H at +128

    int* lc = lcomp[wv];

    lc[lane] = 0;
    if (lane < 32) lc[64 + lane] = 0;

    int nd = (lane < 8) ? nodes[e * 8 + lane] : 0;
    int hu = 0, hr = 0, hmv = 0;
    if (lane < 50) {
        hu  = hist_u[e * 50 + lane];
        hr  = hist_r[e * 50 + lane];
        hmv = hist_m[e * 50 + lane];
    }
    int sa = 0, sk = 0;
    if (lane < 32) {
        sa = soc_a[e * 32 + lane];
        sk = soc_m[e * 32 + lane];
    }

    uint64_t hb = __ballot(hmv != 0);
    const int hc = (int)__popcll(hb);
    int hrank = (int)__popcll(hb & ((1ull << lane) - 1));

    uint64_t sbm = __ballot(sk != 0);
    const int scn = (int)__popcll(sbm);
    int srank = (int)__popcll(sbm & ((1ull << lane) - 1));

    const float hw = 0.5f / (float)hc;     // hc >= 1 (mask[:,0]=True)
    const float sw = 0.5f / (float)scn;    // scn >= 1
    const int   n  = hc + scn;             // <= 82

    if (hmv) lc[hrank] = (hu << 8) + 128;
    if (sk)  lc[hc + srank] = (sa << 8) + 128;

    const int c0 = (int)__popcll(__ballot(hmv && hr == 0));
    const int c1 = (int)__popcll(__ballot(hmv && hr == 1));
    const int c2 = (int)__popcll(__ballot(hmv && hr == 2));
    const int c3 = (int)__popcll(__ballot(hmv && hr == 3));
    const int c4 = (int)__popcll(__ballot(hmv && hr == 4));

    int pkA = lc[lane];
    int pkB = lc[64 + (lane & 31)];

    float sc = (lane < 8) ? Q[nd] : -1e30f;
    float mx = sc;
    mx = fmaxf(mx, __shfl_xor(mx, 1));
    mx = fmaxf(mx, __shfl_xor(mx, 2));
    mx = fmaxf(mx, __shfl_xor(mx, 4));
    float ex = __expf(sc - mx);
    float sm = ex;
    sm += __shfl_xor(sm, 1);
    sm += __shfl_xor(sm, 2);
    sm += __shfl_xor(sm, 4);
    float al = ex / sm;                 // valid on lanes 0..7

    float4 sf4;
    {
        const float a0 = __shfl(al, grp);
        const int   u0 = __shfl(nd, grp);
        const float a1 = __shfl(al, 4 + grp);
        const int   u1 = __shfl(nd, 4 + grp);
        const float4 v0 = hf4_to_f4(*(const ushort4*)(fb + ((unsigned)u0 << 8) + sub * 8));
        const float4 v1 = hf4_to_f4(*(const ushort4*)(fb + ((unsigned)u1 << 8) + sub * 8));
        sf4.x = a0 * v0.x + a1 * v1.x;
        sf4.y = a0 * v0.y + a1 * v1.y;
        sf4.z = a0 * v0.z + a1 * v1.z;
        sf4.w = a0 * v0.w + a1 * v1.w;
    }

    float4 nb4 = {0.f, 0.f, 0.f, 0.f};
    for (int base = 0; base < n; base += 16) {
        #pragma unroll
        for (int j = 0; j < 4; ++j) {
            const int cbase = base + j * 4;       // uniform, 4-aligned
            int off;
            if (cbase < 64) off = __shfl(pkA, cbase + grp);
            else            off = __shfl(pkB, cbase - 64 + grp);
            const int idx = cbase + grp;
            const float w = (idx < hc) ? hw : ((idx < n) ? sw : 0.f);
            const float4 v = hf4_to_f4(*(const ushort4*)(fb + (unsigned)off + sub * 8));
            nb4.x += w * v.x; nb4.y += w * v.y;
            nb4.z += w * v.z; nb4.w += w * v.w;
        }
    }

#define XRED(v4)                                            \
    v4.x += __shfl_xor(v4.x, 16); v4.x += __shfl_xor(v4.x, 32); \
    v4.y += __shfl_xor(v4.y, 16); v4.y += __shfl_xor(v4.y, 32); \
    v4.z += __shfl_xor(v4.z, 16); v4.z += __shfl_xor(v4.z, 32); \
    v4.w += __shfl_xor(v4.w, 16); v4.w += __shfl_xor(v4.w, 32);
    XRED(sf4)
    XRED(nb4)
#undef XRED

    {
        const float4* rb4 = (const float4*)RB;
        const float4 r0 = rb4[0 * 16 + sub];
        const float4 r1 = rb4[1 * 16 + sub];
        const float4 r2 = rb4[2 * 16 + sub];
        const float4 r3 = rb4[3 * 16 + sub];
        const float4 r4 = rb4[4 * 16 + sub];
        const float f0 = hw * (float)c0, f1 = hw * (float)c1, f2 = hw * (float)c2,
                    f3 = hw * (float)c3, f4 = hw * (float)c4;
        nb4.x += f0 * r0.x + f1 * r1.x + f2 * r2.x + f3 * r3.x + f4 * r4.x;
        nb4.y += f0 * r0.y + f1 * r1.y + f2 * r2.y + f3 * r3.y + f4 * r4.y;
        nb4.z += f0 * r0.z + f1 * r1.z + f2 * r2.z + f3 * r3.z + f4 * r4.z;
        nb4.w += f0 * r0.w + f1 * r1.w + f2 * r2.w + f3 * r3.w + f4 * r4.w;
    }

    if (grp == 0) {
        const float4 bv = *(const float4*)(b1 + sub * 4);
        float4 o;
        o.x = fmaxf(sf4.x + nb4.x + bv.x, 0.f);
        o.y = fmaxf(sf4.y + nb4.y + bv.y, 0.f);
        o.z = fmaxf(sf4.z + nb4.z + bv.z, 0.f);
        o.w = fmaxf(sf4.w + nb4.w + bv.w, 0.f);
        *(float4*)(out + (size_t)e * 64 + sub * 4) = o;
    }
}

extern "C" void kernel_launch(void* const* d_in, const int* in_sizes, int n_in,
                              void* d_out, int out_size, void* d_ws, size_t ws_size,
                              hipStream_t stream)
{
    const int*   nodes    = (const int*)d_in[0];
    const int*   hu       = (const int*)d_in[1];
    const int*   hr       = (const int*)d_in[2];
    const int*   hm       = (const int*)d_in[3];
    const int*   sa       = (const int*)d_in[4];
    const int*   smk      = (const int*)d_in[5];
    const float* features = (const float*)d_in[6];
    const float* r_embed  = (const float*)d_in[7];
    const float* wg1      = (const float*)d_in[8];
    const float* bg1      = (const float*)d_in[9];
    const float* wg2      = (const float*)d_in[10];
    const float* bg2      = (const float*)d_in[11];
    const float* w1       = (const float*)d_in[12];
    const float* b1       = (const float*)d_in[13];
    float* out = (float*)d_out;

    // ws layout (~26.2 MB):
    float*          Q  = (float*)d_ws;       // 131072 floats reserved
    float*          RB = Q + 131072;         // 512 floats reserved (320 used)
    unsigned short* GH = (unsigned short*)(RB + 512);   // 100000*128 f16 = 25.6 MB

    k0_build<<<(NUSERS + 63) / 64, 256, 0, stream>>>(
        features, r_embed, wg1, bg1, wg2, bg2, w1, Q, RB, GH);
    k1_fuse<<<BB / 4, 256, 0, stream>>>(nodes, hu, hr, hm, sa, smk,
                                        GH, RB, Q, b1, out);
}

// Round 17
// 134.388 us; speedup vs baseline: 1.2402x; 1.0156x over previous
//
#include <hip/hip_runtime.h>
#include <hip/hip_fp16.h>
#include <cstdint>
#include <cstddef>

#define NUSERS 100000
#define BB 16384

typedef __attribute__((ext_vector_type(8))) _Float16 f16x8;
typedef __attribute__((ext_vector_type(4))) float f32x4;

static __device__ __forceinline__ unsigned short f2h(float x) {
    __half h = __float2half_rn(x);
    return *reinterpret_cast<unsigned short*>(&h);
}
static __device__ __forceinline__ float h2f(unsigned short u) {
    __half h = *reinterpret_cast<__half*>(&u);
    return __half2float(h);
}
static __device__ __forceinline__ float4 hf4_to_f4(ushort4 h) {
    float4 r;
    r.x = h2f(h.x); r.y = h2f(h.y); r.z = h2f(h.z); r.w = h2f(h.w);
    return r;
}

// ---------------- K0: f16 G|H table + Q scores, both via MFMA.
// Byte-identical to the round-16 champion (136.5us total; k0 ~8-9us, near
// its ~51MB traffic floor).
__global__ __launch_bounds__(256) void k0_build(
    const float* __restrict__ features, const float* __restrict__ r_embed,
    const float* __restrict__ wg1, const float* __restrict__ bg1,
    const float* __restrict__ wg2, const float* __restrict__ bg2,
    const float* __restrict__ w1,
    float* __restrict__ Q, float* __restrict__ RB,
    unsigned short* __restrict__ GH)
{
    __shared__ unsigned short Al[64 * 72];   // A f16 [user][dim], pad 72
    __shared__ unsigned short Bt[128 * 72];  // w1^T f16 [outcol c'][k=d], pad 72
    __shared__ unsigned short Wg[16 * 72];   // wg1^T f16 [att_k][d], pad 72

    const int tid = threadIdx.x;
    const int blk = blockIdx.x;
    const int u0  = blk * 64;

    // ---- stage A: 64 users x 64 dims (f32 -> f16), zero-fill invalid ----
    #pragma unroll
    for (int q = 0; q < 4; ++q) {
        const int idx = tid + q * 256;       // 0..1023
        const int ul  = idx >> 4, qd = idx & 15;
        float4 v = make_float4(0.f, 0.f, 0.f, 0.f);
        if (u0 + ul < NUSERS)
            v = *(const float4*)(features + (size_t)(u0 + ul) * 64 + qd * 4);
        ushort4 o;
        o.x = f2h(v.x); o.y = f2h(v.y); o.z = f2h(v.z); o.w = f2h(v.w);
        *(ushort4*)&Al[ul * 72 + qd * 4] = o;
    }
    // ---- stage B^T: w1[128][64] -> Bt[c'][d]; c'<64: W1a col, c'>=64: W1b ----
    #pragma unroll
    for (int q = 0; q < 8; ++q) {
        const int idx = tid + q * 256;       // 0..2047
        const int r  = idx >> 4, cq = (idx & 15) * 4;
        const float4 v = *(const float4*)(w1 + r * 64 + cq);
        const int cc = (r < 64) ? cq : (64 + cq);
        const int dd = (r < 64) ? r : (r - 64);
        Bt[(cc + 0) * 72 + dd] = f2h(v.x);
        Bt[(cc + 1) * 72 + dd] = f2h(v.y);
        Bt[(cc + 2) * 72 + dd] = f2h(v.z);
        Bt[(cc + 3) * 72 + dd] = f2h(v.w);
    }
    // ---- stage wg1^T as f16 for the Q MFMA ----
    {
        const float4 w = ((const float4*)wg1)[tid];   // d=tid>>2, k0=(tid&3)*4
        const int d = tid >> 2, kq = (tid & 3) * 4;
        Wg[(kq + 0) * 72 + d] = f2h(w.x);
        Wg[(kq + 1) * 72 + d] = f2h(w.y);
        Wg[(kq + 2) * 72 + d] = f2h(w.z);
        Wg[(kq + 3) * 72 + d] = f2h(w.w);
    }
    __syncthreads();

    // ---- MFMA 1: GH — wave wv owns users wv*16..+15, 128 cols, K=64 ----
    const int lane = tid & 63, wv = tid >> 6;
    const int arow = wv * 16 + (lane & 15);
    const int hi   = lane >> 4;
    f32x4 acc[8];
    #pragma unroll
    for (int ct = 0; ct < 8; ++ct) acc[ct] = (f32x4){0.f, 0.f, 0.f, 0.f};
    f32x4 qacc = (f32x4){0.f, 0.f, 0.f, 0.f};
    #pragma unroll
    for (int ks = 0; ks < 2; ++ks) {
        const f16x8 a = *(const f16x8*)&Al[arow * 72 + ks * 32 + hi * 8];
        #pragma unroll
        for (int ct = 0; ct < 8; ++ct) {
            const f16x8 b = *(const f16x8*)&Bt[(ct * 16 + (lane & 15)) * 72 + ks * 32 + hi * 8];
            acc[ct] = __builtin_amdgcn_mfma_f32_16x16x32_f16(a, b, acc[ct], 0, 0, 0);
        }
        // ---- MFMA 2: Q logits — S = F @ wg1 (16 att cols) ----
        const f16x8 bq = *(const f16x8*)&Wg[(lane & 15) * 72 + ks * 32 + hi * 8];
        qacc = __builtin_amdgcn_mfma_f32_16x16x32_f16(a, bq, qacc, 0, 0, 0);
    }

    // ---- store GH as f16, lane-pair packed u32 (cols 2m|2m+1) ----
    #pragma unroll
    for (int ct = 0; ct < 8; ++ct) {
        #pragma unroll
        for (int j = 0; j < 4; ++j) {
            const float own  = acc[ct][j];
            const float part = __shfl_xor(own, 1);   // col c^1
            const int u = u0 + wv * 16 + hi * 4 + j;
            if (((lane & 1) == 0) && u < NUSERS) {
                const int c = ct * 16 + (lane & 15);         // even
                const unsigned val = (unsigned)f2h(own) | ((unsigned)f2h(part) << 16);
                *(unsigned*)(GH + (size_t)u * 128 + c) = val;
            }
        }
    }

    // ---- Q: tanh(S + bg1) * wg2, reduce over the 16 att cols ----
    {
        const float bg1v = bg1[lane & 15];
        const float wk2  = wg2[lane & 15];
        const float bg2v = bg2[0];
        #pragma unroll
        for (int j = 0; j < 4; ++j) {
            const float s = qacc[j] + bg1v;
            const float xx = fminf(fmaxf(s, -9.f), 9.f);
            const float e2 = __expf(2.f * xx);
            float t = (e2 - 1.f) / (e2 + 1.f) * wk2;
            t += __shfl_xor(t, 1);
            t += __shfl_xor(t, 2);
            t += __shfl_xor(t, 4);
            t += __shfl_xor(t, 8);
            const int u = u0 + wv * 16 + hi * 4 + j;
            if (((lane & 15) == 0) && u < NUSERS) Q[u] = t + bg2v;
        }
    }

    // ---- RB = r_embed @ W1b (block 0 only; exact f32) ----
    if (blk == 0) {
        for (int t = tid; t < 320; t += 256) {
            const int r = t >> 6, c = t & 63;
            float a = 0.f;
            #pragma unroll 8
            for (int d = 0; d < 64; ++d)
                a += r_embed[r * 64 + d] * w1[(64 + d) * 64 + c];
            RB[r * 64 + c] = a;
        }
    }
}

// ---------------- K1 v2: ONE merged gather list (members + neighbors),
// ONE accumulator, ONE cross-group reduction.
// Round-16 analysis: k1's warm cost (~27us, VALUBusy 41%) is spread across
// ~450 ops/wave with no dominant block. Since out = relu(sf+nb+rc+b1), sf
// and nb never needed separate accumulators. Members enter the merged list
// as entries 0..7 (offset -> G half, weight = alpha); neighbors follow
// (offset -> H half, weight hw/sw). (offset,weight) packed in one LDS int2
// -> one ds_read_b64 per entry replaces {shfl + weight-select VALU}.
// Deletes the member phase, one full XRED, pkA/pkB readback, the uniform
// branch, and ~64 weight-select VALU (~-100 ops/wave of ~450).
// Numerics: pure f32 reordering (~1e-7); same precision everywhere.
__global__ __launch_bounds__(256) void k1_fuse(
    const int* __restrict__ nodes, const int* __restrict__ hist_u,
    const int* __restrict__ hist_r, const int* __restrict__ hist_m,
    const int* __restrict__ soc_a, const int* __restrict__ soc_m,
    const unsigned short* __restrict__ GH, const float* __restrict__ RB,
    const float* __restrict__ Q, const float* __restrict__ b1,
    float* __restrict__ out)
{
    __shared__ int2 ew[4][96];        // 3072B: per-wave merged (offset, weight)

    const int tid  = threadIdx.x;
    const int lane = tid & 63;
    const int wv   = tid >> 6;
    const int e    = blockIdx.x * 4 + wv;
    const int sub  = lane & 15;       // dim quad
    const int grp  = lane >> 4;       // row slot
    const char* fb = (const char*)GH; // user record = 256B: G at +0, H at +128

    int2* lst = ew[wv];

    // ---- zero-init list (tail: offset 0 = G row of user 0, weight 0) ----
    lst[lane] = make_int2(0, 0);
    if (lane < 32) lst[64 + lane] = make_int2(0, 0);

    // ---- index loads (issue ASAP); Q[nd] is the only dependent load ----
    int nd = (lane < 8) ? nodes[e * 8 + lane] : 0;
    float sc = (lane < 8) ? Q[nd] : -1e30f;
    int hu = 0, hr = 0, hmv = 0;
    if (lane < 50) {
        hu  = hist_u[e * 50 + lane];
        hr  = hist_r[e * 50 + lane];
        hmv = hist_m[e * 50 + lane];
    }
    int sa = 0, sk = 0;
    if (lane < 32) {
        sa = soc_a[e * 32 + lane];
        sk = soc_m[e * 32 + lane];
    }

    // ---- ballots / counts ----
    uint64_t hb = __ballot(hmv != 0);
    const int hc = (int)__popcll(hb);
    int hrank = (int)__popcll(hb & ((1ull << lane) - 1));

    uint64_t sbm = __ballot(sk != 0);
    const int scn = (int)__popcll(sbm);
    int srank = (int)__popcll(sbm & ((1ull << lane) - 1));

    const float hw = 0.5f / (float)hc;     // hc >= 1 (mask[:,0]=True)
    const float sw = 0.5f / (float)scn;    // scn >= 1
    const int   ntot = 8 + hc + scn;       // <= 90 (entries fit 96; idx<=95)

    // ---- compaction: members [0,8) filled after softmax; hist [8,8+hc),
    //      social [8+hc, ntot). Neighbor offsets point at the H half. ----
    if (hmv) lst[8 + hrank]      = make_int2((hu << 8) + 128, __float_as_int(hw));
    if (sk)  lst[8 + hc + srank] = make_int2((sa << 8) + 128, __float_as_int(sw));

    // ---- rating counts ----
    const int c0 = (int)__popcll(__ballot(hmv && hr == 0));
    const int c1 = (int)__popcll(__ballot(hmv && hr == 1));
    const int c2 = (int)__popcll(__ballot(hmv && hr == 2));
    const int c3 = (int)__popcll(__ballot(hmv && hr == 3));
    const int c4 = (int)__popcll(__ballot(hmv && hr == 4));

    // ---- softmax over 8 group logits (lanes 0..7) ----
    float mx = sc;
    mx = fmaxf(mx, __shfl_xor(mx, 1));
    mx = fmaxf(mx, __shfl_xor(mx, 2));
    mx = fmaxf(mx, __shfl_xor(mx, 4));
    float ex = __expf(sc - mx);
    float sm = ex;
    sm += __shfl_xor(sm, 1);
    sm += __shfl_xor(sm, 2);
    sm += __shfl_xor(sm, 4);
    const float al = ex / sm;           // valid on lanes 0..7

    // ---- member entries: offset -> G half (+0), weight = alpha ----
    if (lane < 8) lst[lane] = make_int2(nd << 8, __float_as_int(al));

    // ---- ONE merged gather loop: 16 rows (4 independent loads) per iter ----
    float4 acc = {0.f, 0.f, 0.f, 0.f};
    for (int base = 0; base < ntot; base += 16) {
        #pragma unroll
        for (int j = 0; j < 4; ++j) {
            const int2 p = lst[base + j * 4 + grp];        // ds_read_b64
            const float w = __int_as_float(p.y);
            const float4 v = hf4_to_f4(*(const ushort4*)(fb + (unsigned)p.x + sub * 8));
            acc.x += w * v.x; acc.y += w * v.y;
            acc.z += w * v.z; acc.w += w * v.w;
        }
    }

    // ---- ONE cross-group reduction ----
    acc.x += __shfl_xor(acc.x, 16); acc.x += __shfl_xor(acc.x, 32);
    acc.y += __shfl_xor(acc.y, 16); acc.y += __shfl_xor(acc.y, 32);
    acc.z += __shfl_xor(acc.z, 16); acc.z += __shfl_xor(acc.z, 32);
    acc.w += __shfl_xor(acc.w, 16); acc.w += __shfl_xor(acc.w, 32);

    // ---- rating-count correction via RB = r_embed@W1b (exact f32) ----
    {
        const float4* rb4 = (const float4*)RB;
        const float4 r0 = rb4[0 * 16 + sub];
        const float4 r1 = rb4[1 * 16 + sub];
        const float4 r2 = rb4[2 * 16 + sub];
        const float4 r3 = rb4[3 * 16 + sub];
        const float4 r4 = rb4[4 * 16 + sub];
        const float f0 = hw * (float)c0, f1 = hw * (float)c1, f2 = hw * (float)c2,
                    f3 = hw * (float)c3, f4 = hw * (float)c4;
        acc.x += f0 * r0.x + f1 * r1.x + f2 * r2.x + f3 * r3.x + f4 * r4.x;
        acc.y += f0 * r0.y + f1 * r1.y + f2 * r2.y + f3 * r3.y + f4 * r4.y;
        acc.z += f0 * r0.z + f1 * r1.z + f2 * r2.z + f3 * r3.z + f4 * r4.z;
        acc.w += f0 * r0.w + f1 * r1.w + f2 * r2.w + f3 * r3.w + f4 * r4.w;
    }

    // ---- output: relu(acc + b1), direct store from grp==0 ----
    if (grp == 0) {
        const float4 bv = *(const float4*)(b1 + sub * 4);
        float4 o;
        o.x = fmaxf(acc.x + bv.x, 0.f);
        o.y = fmaxf(acc.y + bv.y, 0.f);
        o.z = fmaxf(acc.z + bv.z, 0.f);
        o.w = fmaxf(acc.w + bv.w, 0.f);
        *(float4*)(out + (size_t)e * 64 + sub * 4) = o;
    }
}

extern "C" void kernel_launch(void* const* d_in, const int* in_sizes, int n_in,
                              void* d_out, int out_size, void* d_ws, size_t ws_size,
                              hipStream_t stream)
{
    const int*   nodes    = (const int*)d_in[0];
    const int*   hu       = (const int*)d_in[1];
    const int*   hr       = (const int*)d_in[2];
    const int*   hm       = (const int*)d_in[3];
    const int*   sa       = (const int*)d_in[4];
    const int*   smk      = (const int*)d_in[5];
    const float* features = (const float*)d_in[6];
    const float* r_embed  = (const float*)d_in[7];
    const float* wg1      = (const float*)d_in[8];
    const float* bg1      = (const float*)d_in[9];
    const float* wg2      = (const float*)d_in[10];
    const float* bg2      = (const float*)d_in[11];
    const float* w1       = (const float*)d_in[12];
    const float* b1       = (const float*)d_in[13];
    float* out = (float*)d_out;

    // ws layout (~26.2 MB):
    float*          Q  = (float*)d_ws;       // 131072 floats reserved
    float*          RB = Q + 131072;         // 512 floats reserved (320 used)
    unsigned short* GH = (unsigned short*)(RB + 512);   // 100000*128 f16 = 25.6 MB

    k0_build<<<(NUSERS + 63) / 64, 256, 0, stream>>>(
        features, r_embed, wg1, bg1, wg2, bg2, w1, Q, RB, GH);
    k1_fuse<<<BB / 4, 256, 0, stream>>>(nodes, hu, hr, hm, sa, smk,
                                        GH, RB, Q, b1, out);
}

// Round 18
// 133.607 us; speedup vs baseline: 1.2474x; 1.0059x over previous
//
#include <hip/hip_runtime.h>
#include <hip/hip_fp16.h>
#include <cstdint>
#include <cstddef>

#define NUSERS 100000
#define BB 16384

typedef __attribute__((ext_vector_type(8))) _Float16 f16x8;
typedef __attribute__((ext_vector_type(4))) float f32x4;

// Record layout per user (192 B): G f16[64] @ +0 (members, weight<=1),
// H fp8-e4m3[64] @ +128, pre-scaled x64 (neighbors, weight ~0.01, averaged).
#define REC 192

static __device__ __forceinline__ unsigned short f2h(float x) {
    __half h = __float2half_rn(x);
    return *reinterpret_cast<unsigned short*>(&h);
}
static __device__ __forceinline__ float h2f(unsigned short u) {
    __half h = *reinterpret_cast<__half*>(&u);
    return __half2float(h);
}
static __device__ __forceinline__ float4 hf4_to_f4(ushort4 h) {
    float4 r;
    r.x = h2f(h.x); r.y = h2f(h.y); r.z = h2f(h.z); r.w = h2f(h.w);
    return r;
}
static __device__ __forceinline__ void accp8(float4& acc, unsigned ub, float w) {
    acc.x += w * __builtin_amdgcn_cvt_f32_fp8((int)ub, 0);
    acc.y += w * __builtin_amdgcn_cvt_f32_fp8((int)ub, 1);
    acc.z += w * __builtin_amdgcn_cvt_f32_fp8((int)ub, 2);
    acc.w += w * __builtin_amdgcn_cvt_f32_fp8((int)ub, 3);
}

// ---------------- K0: G(f16) | H(fp8 x64) table + Q scores, both via MFMA.
// Same structure as the round-16/17 champion k0; only the GH store path
// changed (H half: x64 scale -> cvt_pk_fp8 -> 2-byte store).
__global__ __launch_bounds__(256) void k0_build(
    const float* __restrict__ features, const float* __restrict__ r_embed,
    const float* __restrict__ wg1, const float* __restrict__ bg1,
    const float* __restrict__ wg2, const float* __restrict__ bg2,
    const float* __restrict__ w1,
    float* __restrict__ Q, float* __restrict__ RB,
    unsigned char* __restrict__ GHb)
{
    __shared__ unsigned short Al[64 * 72];   // A f16 [user][dim], pad 72
    __shared__ unsigned short Bt[128 * 72];  // w1^T f16 [outcol c'][k=d], pad 72
    __shared__ unsigned short Wg[16 * 72];   // wg1^T f16 [att_k][d], pad 72

    const int tid = threadIdx.x;
    const int blk = blockIdx.x;
    const int u0  = blk * 64;

    // ---- stage A: 64 users x 64 dims (f32 -> f16), zero-fill invalid ----
    #pragma unroll
    for (int q = 0; q < 4; ++q) {
        const int idx = tid + q * 256;       // 0..1023
        const int ul  = idx >> 4, qd = idx & 15;
        float4 v = make_float4(0.f, 0.f, 0.f, 0.f);
        if (u0 + ul < NUSERS)
            v = *(const float4*)(features + (size_t)(u0 + ul) * 64 + qd * 4);
        ushort4 o;
        o.x = f2h(v.x); o.y = f2h(v.y); o.z = f2h(v.z); o.w = f2h(v.w);
        *(ushort4*)&Al[ul * 72 + qd * 4] = o;
    }
    // ---- stage B^T: w1[128][64] -> Bt[c'][d]; c'<64: W1a col, c'>=64: W1b ----
    #pragma unroll
    for (int q = 0; q < 8; ++q) {
        const int idx = tid + q * 256;       // 0..2047
        const int r  = idx >> 4, cq = (idx & 15) * 4;
        const float4 v = *(const float4*)(w1 + r * 64 + cq);
        const int cc = (r < 64) ? cq : (64 + cq);
        const int dd = (r < 64) ? r : (r - 64);
        Bt[(cc + 0) * 72 + dd] = f2h(v.x);
        Bt[(cc + 1) * 72 + dd] = f2h(v.y);
        Bt[(cc + 2) * 72 + dd] = f2h(v.z);
        Bt[(cc + 3) * 72 + dd] = f2h(v.w);
    }
    // ---- stage wg1^T as f16 for the Q MFMA ----
    {
        const float4 w = ((const float4*)wg1)[tid];   // d=tid>>2, k0=(tid&3)*4
        const int d = tid >> 2, kq = (tid & 3) * 4;
        Wg[(kq + 0) * 72 + d] = f2h(w.x);
        Wg[(kq + 1) * 72 + d] = f2h(w.y);
        Wg[(kq + 2) * 72 + d] = f2h(w.z);
        Wg[(kq + 3) * 72 + d] = f2h(w.w);
    }
    __syncthreads();

    // ---- MFMA 1: GH — wave wv owns users wv*16..+15, 128 cols, K=64 ----
    const int lane = tid & 63, wv = tid >> 6;
    const int arow = wv * 16 + (lane & 15);
    const int hi   = lane >> 4;
    f32x4 acc[8];
    #pragma unroll
    for (int ct = 0; ct < 8; ++ct) acc[ct] = (f32x4){0.f, 0.f, 0.f, 0.f};
    f32x4 qacc = (f32x4){0.f, 0.f, 0.f, 0.f};
    #pragma unroll
    for (int ks = 0; ks < 2; ++ks) {
        const f16x8 a = *(const f16x8*)&Al[arow * 72 + ks * 32 + hi * 8];
        #pragma unroll
        for (int ct = 0; ct < 8; ++ct) {
            const f16x8 b = *(const f16x8*)&Bt[(ct * 16 + (lane & 15)) * 72 + ks * 32 + hi * 8];
            acc[ct] = __builtin_amdgcn_mfma_f32_16x16x32_f16(a, b, acc[ct], 0, 0, 0);
        }
        // ---- MFMA 2: Q logits — S = F @ wg1 (16 att cols) ----
        const f16x8 bq = *(const f16x8*)&Wg[(lane & 15) * 72 + ks * 32 + hi * 8];
        qacc = __builtin_amdgcn_mfma_f32_16x16x32_f16(a, bq, qacc, 0, 0, 0);
    }

    // ---- store G (f16, cols 0-63) and H (fp8 x64, cols 64-127) ----
    // C/D layout: col = ct*16 + (lane&15), row = wv*16 + hi*4 + j  [m89]
    #pragma unroll
    for (int ct = 0; ct < 8; ++ct) {
        #pragma unroll
        for (int j = 0; j < 4; ++j) {
            const float own  = acc[ct][j];
            const float part = __shfl_xor(own, 1);   // col c^1
            const int u = u0 + wv * 16 + hi * 4 + j;
            if (((lane & 1) == 0) && u < NUSERS) {
                const int c = ct * 16 + (lane & 15);         // even
                if (ct < 4) {
                    const unsigned val = (unsigned)f2h(own) | ((unsigned)f2h(part) << 16);
                    *(unsigned*)(GHb + (size_t)u * REC + 2 * c) = val;
                } else {
                    const int pk = __builtin_amdgcn_cvt_pk_fp8_f32(
                        own * 64.f, part * 64.f, 0, false);
                    *(unsigned short*)(GHb + (size_t)u * REC + 128 + (c - 64)) =
                        (unsigned short)(pk & 0xFFFF);
                }
            }
        }
    }

    // ---- Q: tanh(S + bg1) * wg2, reduce over the 16 att cols ----
    {
        const float bg1v = bg1[lane & 15];
        const float wk2  = wg2[lane & 15];
        const float bg2v = bg2[0];
        #pragma unroll
        for (int j = 0; j < 4; ++j) {
            const float s = qacc[j] + bg1v;
            const float xx = fminf(fmaxf(s, -9.f), 9.f);
            const float e2 = __expf(2.f * xx);
            float t = (e2 - 1.f) / (e2 + 1.f) * wk2;
            t += __shfl_xor(t, 1);
            t += __shfl_xor(t, 2);
            t += __shfl_xor(t, 4);
            t += __shfl_xor(t, 8);
            const int u = u0 + wv * 16 + hi * 4 + j;
            if (((lane & 15) == 0) && u < NUSERS) Q[u] = t + bg2v;
        }
    }

    // ---- RB = r_embed @ W1b (block 0 only; exact f32) ----
    if (blk == 0) {
        for (int t = tid; t < 320; t += 256) {
            const int r = t >> 6, c = t & 63;
            float a = 0.f;
            #pragma unroll 8
            for (int d = 0; d < 64; ++d)
                a += r_embed[r * 64 + d] * w1[(64 + d) * 64 + c];
            RB[r * 64 + c] = a;
        }
    }
}

// ---------------- K1 v3: merged list; members read f16 G rows (entries 0-7,
// exactly the first two quads -> peeled), neighbors read fp8 H rows (64B =
// ONE cache line per row instead of two). 1/64 decode scale folded into the
// stored neighbor weights. Tail entries point at offset 128 (finite fp8
// data, weight 0) — never at G bytes, which could decode as fp8 NaN.
__global__ __launch_bounds__(256) void k1_fuse(
    const int* __restrict__ nodes, const int* __restrict__ hist_u,
    const int* __restrict__ hist_r, const int* __restrict__ hist_m,
    const int* __restrict__ soc_a, const int* __restrict__ soc_m,
    const unsigned char* __restrict__ GHb, const float* __restrict__ RB,
    const float* __restrict__ Q, const float* __restrict__ b1,
    float* __restrict__ out)
{
    __shared__ int2 ew[4][96];        // 3072B: per-wave merged (offset, weight)

    const int tid  = threadIdx.x;
    const int lane = tid & 63;
    const int wv   = tid >> 6;
    const int e    = blockIdx.x * 4 + wv;
    const int sub  = lane & 15;       // dim quad
    const int grp  = lane >> 4;       // row slot
    const char* fb = (const char*)GHb;

    int2* lst = ew[wv];

    // ---- init list; tail = (128, 0): finite fp8 row, weight 0 ----
    lst[lane] = make_int2(128, 0);
    if (lane < 32) lst[64 + lane] = make_int2(128, 0);

    // ---- index loads (issue ASAP); Q[nd] is the only dependent load ----
    int nd = (lane < 8) ? nodes[e * 8 + lane] : 0;
    float sc = (lane < 8) ? Q[nd] : -1e30f;
    int hu = 0, hr = 0, hmv = 0;
    if (lane < 50) {
        hu  = hist_u[e * 50 + lane];
        hr  = hist_r[e * 50 + lane];
        hmv = hist_m[e * 50 + lane];
    }
    int sa = 0, sk = 0;
    if (lane < 32) {
        sa = soc_a[e * 32 + lane];
        sk = soc_m[e * 32 + lane];
    }

    // ---- ballots / counts ----
    uint64_t hb = __ballot(hmv != 0);
    const int hc = (int)__popcll(hb);
    int hrank = (int)__popcll(hb & ((1ull << lane) - 1));

    uint64_t sbm = __ballot(sk != 0);
    const int scn = (int)__popcll(sbm);
    int srank = (int)__popcll(sbm & ((1ull << lane) - 1));

    const float hw = 0.5f / (float)hc;     // hc >= 1 (mask[:,0]=True)
    const float sw = 0.5f / (float)scn;    // scn >= 1
    const float S  = 1.f / 64.f;           // fp8 decode scale (H stored x64)
    const int   ntot = 8 + hc + scn;       // <= 90 (fits 96)

    // ---- compaction: members [0,8) after softmax; hist [8,8+hc),
    //      social [8+hc, ntot). Neighbor offsets -> fp8 H half (+128). ----
    if (hmv) lst[8 + hrank]      = make_int2(hu * REC + 128, __float_as_int(hw * S));
    if (sk)  lst[8 + hc + srank] = make_int2(sa * REC + 128, __float_as_int(sw * S));

    // ---- rating counts ----
    const int c0 = (int)__popcll(__ballot(hmv && hr == 0));
    const int c1 = (int)__popcll(__ballot(hmv && hr == 1));
    const int c2 = (int)__popcll(__ballot(hmv && hr == 2));
    const int c3 = (int)__popcll(__ballot(hmv && hr == 3));
    const int c4 = (int)__popcll(__ballot(hmv && hr == 4));

    // ---- softmax over 8 group logits (lanes 0..7) ----
    float mx = sc;
    mx = fmaxf(mx, __shfl_xor(mx, 1));
    mx = fmaxf(mx, __shfl_xor(mx, 2));
    mx = fmaxf(mx, __shfl_xor(mx, 4));
    float ex = __expf(sc - mx);
    float sm = ex;
    sm += __shfl_xor(sm, 1);
    sm += __shfl_xor(sm, 2);
    sm += __shfl_xor(sm, 4);
    const float al = ex / sm;           // valid on lanes 0..7

    // ---- member entries: offset -> f16 G half (+0), weight = alpha ----
    if (lane < 8) lst[lane] = make_int2(nd * REC, __float_as_int(al));

    float4 acc = {0.f, 0.f, 0.f, 0.f};

    // ---- peeled iteration 0: entries 0-7 = members (f16 path),
    //      entries 8-15 = first neighbors (fp8 path) ----
    {
        #pragma unroll
        for (int j = 0; j < 2; ++j) {                  // f16 G quads
            const int2 p = lst[j * 4 + grp];
            const float w = __int_as_float(p.y);
            const float4 v = hf4_to_f4(*(const ushort4*)(fb + (unsigned)p.x + sub * 8));
            acc.x += w * v.x; acc.y += w * v.y;
            acc.z += w * v.z; acc.w += w * v.w;
        }
        #pragma unroll
        for (int j = 2; j < 4; ++j) {                  // fp8 H quads
            const int2 p = lst[j * 4 + grp];
            const float w = __int_as_float(p.y);
            const unsigned ub = *(const unsigned*)(fb + (unsigned)p.x + sub * 4);
            accp8(acc, ub, w);
        }
    }

    // ---- remaining merged gathers: all fp8, 16 rows (4 loads) per iter ----
    for (int base = 16; base < ntot; base += 16) {
        #pragma unroll
        for (int j = 0; j < 4; ++j) {
            const int2 p = lst[base + j * 4 + grp];    // ds_read_b64
            const float w = __int_as_float(p.y);
            const unsigned ub = *(const unsigned*)(fb + (unsigned)p.x + sub * 4);
            accp8(acc, ub, w);
        }
    }

    // ---- ONE cross-group reduction ----
    acc.x += __shfl_xor(acc.x, 16); acc.x += __shfl_xor(acc.x, 32);
    acc.y += __shfl_xor(acc.y, 16); acc.y += __shfl_xor(acc.y, 32);
    acc.z += __shfl_xor(acc.z, 16); acc.z += __shfl_xor(acc.z, 32);
    acc.w += __shfl_xor(acc.w, 16); acc.w += __shfl_xor(acc.w, 32);

    // ---- rating-count correction via RB = r_embed@W1b (exact f32) ----
    {
        const float4* rb4 = (const float4*)RB;
        const float4 r0 = rb4[0 * 16 + sub];
        const float4 r1 = rb4[1 * 16 + sub];
        const float4 r2 = rb4[2 * 16 + sub];
        const float4 r3 = rb4[3 * 16 + sub];
        const float4 r4 = rb4[4 * 16 + sub];
        const float f0 = hw * (float)c0, f1 = hw * (float)c1, f2 = hw * (float)c2,
                    f3 = hw * (float)c3, f4 = hw * (float)c4;
        acc.x += f0 * r0.x + f1 * r1.x + f2 * r2.x + f3 * r3.x + f4 * r4.x;
        acc.y += f0 * r0.y + f1 * r1.y + f2 * r2.y + f3 * r3.y + f4 * r4.y;
        acc.z += f0 * r0.z + f1 * r1.z + f2 * r2.z + f3 * r3.z + f4 * r4.z;
        acc.w += f0 * r0.w + f1 * r1.w + f2 * r2.w + f3 * r3.w + f4 * r4.w;
    }

    // ---- output: relu(acc + b1), direct store from grp==0 ----
    if (grp == 0) {
        const float4 bv = *(const float4*)(b1 + sub * 4);
        float4 o;
        o.x = fmaxf(acc.x + bv.x, 0.f);
        o.y = fmaxf(acc.y + bv.y, 0.f);
        o.z = fmaxf(acc.z + bv.z, 0.f);
        o.w = fmaxf(acc.w + bv.w, 0.f);
        *(float4*)(out + (size_t)e * 64 + sub * 4) = o;
    }
}

extern "C" void kernel_launch(void* const* d_in, const int* in_sizes, int n_in,
                              void* d_out, int out_size, void* d_ws, size_t ws_size,
                              hipStream_t stream)
{
    const int*   nodes    = (const int*)d_in[0];
    const int*   hu       = (const int*)d_in[1];
    const int*   hr       = (const int*)d_in[2];
    const int*   hm       = (const int*)d_in[3];
    const int*   sa       = (const int*)d_in[4];
    const int*   smk      = (const int*)d_in[5];
    const float* features = (const float*)d_in[6];
    const float* r_embed  = (const float*)d_in[7];
    const float* wg1      = (const float*)d_in[8];
    const float* bg1      = (const float*)d_in[9];
    const float* wg2      = (const float*)d_in[10];
    const float* bg2      = (const float*)d_in[11];
    const float* w1       = (const float*)d_in[12];
    const float* b1       = (const float*)d_in[13];
    float* out = (float*)d_out;

    // ws layout (~19.8 MB):
    float*         Q   = (float*)d_ws;       // 131072 floats reserved
    float*         RB  = Q + 131072;         // 512 floats reserved (320 used)
    unsigned char* GHb = (unsigned char*)(RB + 512);    // 100000*192 B = 19.2 MB

    k0_build<<<(NUSERS + 63) / 64, 256, 0, stream>>>(
        features, r_embed, wg1, bg1, wg2, bg2, w1, Q, RB, GHb);
    k1_fuse<<<BB / 4, 256, 0, stream>>>(nodes, hu, hr, hm, sa, smk,
                                        GHb, RB, Q, b1, out);
}